// Round 1
// baseline (276.623 us; speedup 1.0000x reference)
//
#include <hip/hip_runtime.h>

#define BATCH 65536
#define AR 16
#define UD 15
#define SEQ 1024

// One thread per batch row. AR(16) window lives in 16 VGPRs with circular
// indexing resolved at compile time (full unroll). 32 timesteps are staged
// in a per-wave LDS tile and flushed transposed for coalesced global writes.
__global__ __launch_bounds__(64) void arx_kernel(
    const float* __restrict__ y,
    const float* __restrict__ u,
    const float* __restrict__ w,
    float* __restrict__ out)
{
    // [64][33]: +1 pad -> ds_write bank = (lane + col) % 32, conflict-free;
    // flush read pattern is 2-way aliased which is free on gfx950 (m136).
    __shared__ float buf[64][33];

    const int lane = threadIdx.x;          // 0..63
    const int row0 = blockIdx.x * 64;
    const int row  = row0 + lane;

    // w is wave-uniform -> compiler keeps these in SGPRs.
    float w_ar[AR];
#pragma unroll
    for (int k = 0; k < AR; ++k) w_ar[k] = w[k];

    // const term: u . w_u + bias
    float cst = w[AR + UD];
#pragma unroll
    for (int j = 0; j < UD; ++j) cst = fmaf(u[row * UD + j], w[AR + j], cst);

    // initial window = y row (4x float4-equivalent contiguous 64B per lane)
    float win[AR];
#pragma unroll
    for (int k = 0; k < AR; ++k) win[k] = y[row * AR + k];

    const int half = lane >> 5;   // which 32-lane half
    const int c    = lane & 31;   // column within chunk

    // ---- chunk 0: t = 0..31  (16 y values + preds s=0..15) ----
#pragma unroll
    for (int k = 0; k < AR; ++k) buf[lane][k] = win[k];
#pragma unroll
    for (int j = 0; j < 16; ++j) {
        // two independent 8-tap FMA chains to halve dependency latency
        float p0 = cst, p1 = 0.0f;
#pragma unroll
        for (int k = 0; k < 8; ++k)  p0 = fmaf(win[(j + k) & 15], w_ar[k], p0);
#pragma unroll
        for (int k = 8; k < 16; ++k) p1 = fmaf(win[(j + k) & 15], w_ar[k], p1);
        float p = p0 + p1;
        win[j & 15] = p;
        buf[lane][16 + j] = p;
    }
    __syncthreads();   // 1-wave block: compiles to waitcnt (ordering only)
#pragma unroll
    for (int k = 0; k < 32; ++k) {
        // wave instruction writes rows (2k, 2k+1): two contiguous 128B segments
        out[(size_t)(row0 + 2 * k + half) * SEQ + c] = buf[2 * k + half][c];
    }
    __syncthreads();

    // ---- chunks 1..31: 32 preds each; s = 16+(cb-1)*32+j  ==  j (mod 16) ----
    for (int cb = 1; cb < 32; ++cb) {
#pragma unroll
        for (int j = 0; j < 32; ++j) {
            float p0 = cst, p1 = 0.0f;
#pragma unroll
            for (int k = 0; k < 8; ++k)  p0 = fmaf(win[(j + k) & 15], w_ar[k], p0);
#pragma unroll
            for (int k = 8; k < 16; ++k) p1 = fmaf(win[(j + k) & 15], w_ar[k], p1);
            float p = p0 + p1;
            win[j & 15] = p;
            buf[lane][j] = p;
        }
        __syncthreads();
        const int tb = cb * 32;
#pragma unroll
        for (int k = 0; k < 32; ++k) {
            out[(size_t)(row0 + 2 * k + half) * SEQ + tb + c] = buf[2 * k + half][c];
        }
        __syncthreads();
    }
}

extern "C" void kernel_launch(void* const* d_in, const int* in_sizes, int n_in,
                              void* d_out, int out_size, void* d_ws, size_t ws_size,
                              hipStream_t stream) {
    const float* y = (const float*)d_in[0];
    const float* u = (const float*)d_in[1];
    const float* w = (const float*)d_in[2];
    float* out = (float*)d_out;

    arx_kernel<<<dim3(BATCH / 64), dim3(64), 0, stream>>>(y, u, w, out);
}